// Round 3
// baseline (816.600 us; speedup 1.0000x reference)
//
#include <hip/hip_runtime.h>
#include <hip/hip_bf16.h>
#include <stdint.h>

typedef __attribute__((ext_vector_type(8))) short short8;   // 8 bf16 = 4 VGPRs
typedef __attribute__((ext_vector_type(4))) float f32x4;    // MFMA C/D frag

typedef __attribute__((address_space(3))) uint8_t lds_u8;
typedef __attribute__((address_space(1))) uint8_t glb_u8;

__device__ __forceinline__ void load_lds_16(const void* g, void* l) {
    __builtin_amdgcn_global_load_lds((glb_u8*)g, (lds_u8*)l, 16, 0, 0);
}

__device__ __forceinline__ unsigned short f2b(float f) {
    __hip_bfloat16 h = __float2bfloat16(f);
    return __builtin_bit_cast(unsigned short, h);
}
__device__ __forceinline__ ushort2 f2b2(float a, float b) {
    __hip_bfloat162 h = __float22bfloat162_rn(float2{a, b});
    ushort2 r;
    __builtin_memcpy(&r, &h, sizeof(r));
    return r;
}

constexpr int Bz = 32, Ss = 577, Dd = 768, Hh = 12;
constexpr int Mm = Bz * Ss;          // 18464
constexpr int QKV_N = 3 * Dd;        // 2304
constexpr float SCALE_L2E = 0.125f * 1.4426950408889634f;

// ---------------- cast x -> bf16 ----------------
__global__ void cast_f32_bf16(const float* __restrict__ src,
                              unsigned short* __restrict__ dst, int n4) {
    int i = blockIdx.x * blockDim.x + threadIdx.x;
    if (i >= n4) return;
    float4 v = ((const float4*)src)[i];
    ushort4 o;
    o.x = f2b(v.x); o.y = f2b(v.y); o.z = f2b(v.z); o.w = f2b(v.w);
    ((ushort4*)dst)[i] = o;
}

// ---------------- transpose + cast: src fp32 [R][C] -> dst bf16 [C][R] ----------------
__global__ void transpose_cast(const float* __restrict__ src,
                               unsigned short* __restrict__ dst, int R, int C) {
    __shared__ unsigned short tile[32][33];
    int c0 = blockIdx.x * 32, r0 = blockIdx.y * 32;
    int tx = threadIdx.x, ty = threadIdx.y;  // (32,8)
#pragma unroll
    for (int i = 0; i < 4; ++i)
        tile[ty + i * 8][tx] = f2b(src[(size_t)(r0 + ty + i * 8) * C + c0 + tx]);
    __syncthreads();
#pragma unroll
    for (int i = 0; i < 4; ++i) {
        int rr = ty + i * 8;
        dst[(size_t)(c0 + rr) * R + r0 + tx] = tile[tx][rr];
    }
}

// ========== 256xBN 2-phase TN GEMM, BK=32, 2 blocks/CU (counted vmcnt) ==========
// C[M][N_] = A[M][768]*Bt[N_][768]^T + bias.  8 waves (2M x 4N), 24 K-steps.
// LDS/buffer: A 16KB (units A0/A1 of 8KB) + B BN*64B. 2 buffers.
// Unit A_h = tile rows {(lr&63) + (lr>>6)*128 + h*64} so ph0 (m-frags 0..3 of both
// wave-halves) reads only A0, ph1 only A1.  B region is row-linear.
// Stage cadence for T+1: ph0 -> {A0, B0[,B1]}, ph1 -> {A1}.
// Drain rule (other waves' global_load_lds only visible after their vmcnt +
// barrier): vmcnt placed BEFORE each post-MFMA barrier:
//   end ph0: vmcnt(3 | 2 for BN128) drains A1(T)     (needed by ph1(T))
//   end ph1: vmcnt(1)               drains ph0(T+1)'s units (needed by ph0(T+1))
// In-flight never reaches 0 until the last tile (vmcnt 0 there).
// XOR chunk swizzle: content(lr,ch) = global(lr, ch^(lr&3)); read chunk = quad^(lr&3).
template <int N_, int BN, bool OUT_BF16>
__global__ __launch_bounds__(512, 4)
void gemm2ph(const unsigned short* __restrict__ A,
             const unsigned short* __restrict__ Bt,
             const float* __restrict__ bias,
             void* __restrict__ Cout) {
    constexpr int K = 768;
    constexpr int KB = K / 32;             // 24
    constexpr int NF = BN / 64;            // n-frags per wave (4 or 2)
    constexpr int NX = N_ / BN;
    constexpr int NY = (Mm + 255) / 256;   // 73
    constexpr int NWG = NX * NY;
    constexpr int QC = NWG >> 3, RC = NWG & 7;
    constexpr int ABYTES = 16384;
    constexpr int BBYTES = BN * 64;
    constexpr int BUFB = ABYTES + BBYTES;
    extern __shared__ __align__(16) uint8_t smem[];

    const int tid = threadIdx.x;
    const int wave = tid >> 6, lane = tid & 63;
    const int quad = lane >> 4, lc = lane & 15;
    const int wm = wave >> 2, wn = wave & 3;

    // XCD-aware bijective remap (m204)
    const int orig = blockIdx.y * NX + blockIdx.x;
    const int xcd = orig & 7, lid = orig >> 3;
    const int wgid = (xcd < RC ? xcd * (QC + 1) : RC * (QC + 1) + (xcd - RC) * QC) + lid;
    const int tm = (wgid / NX) * 256;
    const int tn = (wgid % NX) * BN;

    // staging: thread covers one 16B chunk: lr = wave*16 + (lane>>2), ch = lane&3
    // pre-swizzled source chunk = ch ^ (lr&3) = (lane&3) ^ ((lane>>2)&3)
    const int lr = wave * 16 + (lane >> 2);
    const int csw = ((lane & 3) ^ ((lane >> 2) & 3)) * 8;
    const unsigned short* aptr[2];
    const unsigned short* bptr[2];
#pragma unroll
    for (int h = 0; h < 2; ++h) {
        int ar = tm + (lr & 63) + (lr >> 6) * 128 + h * 64;
        if (ar >= Mm) ar = Mm - 1;                 // M-tail clamp (store guarded)
        aptr[h] = A + (size_t)ar * K + csw;
        int br = (BN == 128) ? (tn + lr) : (tn + h * 128 + lr);
        bptr[h] = Bt + (size_t)br * K + csw;
    }

    auto stageA = [&](int kb, int h) {
        load_lds_16(aptr[h] + kb * 32,
                    smem + (kb & 1) * BUFB + h * 8192 + wave * 1024);
    };
    auto stageB = [&](int kb, int h) {
        load_lds_16(bptr[h] + kb * 32,
                    smem + (kb & 1) * BUFB + ABYTES + h * 8192 + wave * 1024);
    };

    short8 af[4], bf[NF];
    auto readA = [&](int b, int h) {
        const uint8_t* base = smem + b * BUFB + h * 8192;
#pragma unroll
        for (int i = 0; i < 4; ++i) {
            int rr = wm * 64 + i * 16 + lc;
            af[i] = *(const short8*)(base + rr * 64 + ((quad ^ (rr & 3)) << 4));
        }
    };
    auto readB = [&](int b) {
        const uint8_t* base = smem + b * BUFB + ABYTES;
#pragma unroll
        for (int j = 0; j < NF; ++j) {
            int nr = wn * (BN / 4) + j * 16 + lc;
            bf[j] = *(const short8*)(base + nr * 64 + ((quad ^ (nr & 3)) << 4));
        }
    };

    f32x4 acc[8][NF] = {};
    auto mfmah = [&](int h) {
        __builtin_amdgcn_s_setprio(1);
#pragma unroll
        for (int i = 0; i < 4; ++i)
#pragma unroll
            for (int j = 0; j < NF; ++j)
                acc[h * 4 + i][j] = __builtin_amdgcn_mfma_f32_16x16x32_bf16(
                    af[i], bf[j], acc[h * 4 + i][j], 0, 0, 0);
        __builtin_amdgcn_s_setprio(0);
    };

    // ---- prologue: tile0 units; issue order matters for the counted drains:
    // {A0, B0 [,B1]} first, A1 last.
    stageA(0, 0);
    stageB(0, 0);
    if (BN == 256) stageB(0, 1);
    stageA(0, 1);
    asm volatile("s_waitcnt vmcnt(1)" ::: "memory");   // drain all but A1(t0)
    __builtin_amdgcn_s_barrier();

    for (int T = 0; T < KB; ++T) {
        const int rb = T & 1;
        const bool pf = (T + 1 < KB);
        // ---- ph0: frags A0 x all B ; stage {A0,B*}(T+1)
        readA(rb, 0);
        readB(rb);
        if (pf) {
            stageA(T + 1, 0);
            stageB(T + 1, 0);
            if (BN == 256) stageB(T + 1, 1);
        }
        __builtin_amdgcn_s_barrier();
        asm volatile("s_waitcnt lgkmcnt(0)" ::: "memory");
        mfmah(0);
        // drain A1(T) for ph1 readers (leave T+1's ph0 stages in flight)
        if (pf) {
            if (BN == 256) asm volatile("s_waitcnt vmcnt(3)" ::: "memory");
            else           asm volatile("s_waitcnt vmcnt(2)" ::: "memory");
        } else {
            asm volatile("s_waitcnt vmcnt(0)" ::: "memory");
        }
        __builtin_amdgcn_s_barrier();
        // ---- ph1: frags A1 x all B (bf reused) ; stage {A1}(T+1)
        readA(rb, 1);
        if (pf) stageA(T + 1, 1);
        __builtin_amdgcn_s_barrier();
        asm volatile("s_waitcnt lgkmcnt(0)" ::: "memory");
        mfmah(1);
        // drain {A0,B*}(T+1) for next ph0 readers (leave A1(T+1) in flight)
        if (pf) asm volatile("s_waitcnt vmcnt(1)" ::: "memory");
        __builtin_amdgcn_s_barrier();
    }

    // ---- epilogue: wave-private LDS transpose, coalesced vector stores
    constexpr int EST = NF * 16 + 4;   // f32 stride per row
    float bv[NF];
#pragma unroll
    for (int j = 0; j < NF; ++j) bv[j] = bias[tn + wn * (BN / 4) + j * 16 + lc];

    float* ep = (float*)smem + wave * (16 * EST);
    const int erow = lane >> 2, ec = (lane & 3) * (NF * 4);
#pragma unroll
    for (int ia = 0; ia < 8; ++ia) {
#pragma unroll
        for (int j = 0; j < NF; ++j)
#pragma unroll
            for (int r = 0; r < 4; ++r)
                ep[(quad * 4 + r) * EST + j * 16 + lc] = acc[ia][j][r] + bv[j];
        __threadfence_block();   // wave-local LDS ordering (DS in-order per wave)
        int grow = tm + wm * 128 + ia * 16 + erow;
        if (grow < Mm) {
            int gcol = tn + wn * (BN / 4) + ec;
            if constexpr (NF == 4) {
                float4 c0 = *(float4*)&ep[erow * EST + ec + 0];
                float4 c1 = *(float4*)&ep[erow * EST + ec + 4];
                float4 c2 = *(float4*)&ep[erow * EST + ec + 8];
                float4 c3 = *(float4*)&ep[erow * EST + ec + 12];
                if constexpr (OUT_BF16) {
                    unsigned short o[16];
                    *(ushort2*)&o[0]  = f2b2(c0.x, c0.y);
                    *(ushort2*)&o[2]  = f2b2(c0.z, c0.w);
                    *(ushort2*)&o[4]  = f2b2(c1.x, c1.y);
                    *(ushort2*)&o[6]  = f2b2(c1.z, c1.w);
                    *(ushort2*)&o[8]  = f2b2(c2.x, c2.y);
                    *(ushort2*)&o[10] = f2b2(c2.z, c2.w);
                    *(ushort2*)&o[12] = f2b2(c3.x, c3.y);
                    *(ushort2*)&o[14] = f2b2(c3.z, c3.w);
                    unsigned short* op = (unsigned short*)Cout + (size_t)grow * N_ + gcol;
                    *(short8*)(op + 0) = *(short8*)&o[0];
                    *(short8*)(op + 8) = *(short8*)&o[8];
                } else {
                    float* op = (float*)Cout + (size_t)grow * N_ + gcol;
                    *(float4*)(op + 0)  = c0;
                    *(float4*)(op + 4)  = c1;
                    *(float4*)(op + 8)  = c2;
                    *(float4*)(op + 12) = c3;
                }
            } else {
                float4 c0 = *(float4*)&ep[erow * EST + ec + 0];
                float4 c1 = *(float4*)&ep[erow * EST + ec + 4];
                float* op = (float*)Cout + (size_t)grow * N_ + gcol;
                *(float4*)(op + 0) = c0;
                *(float4*)(op + 4) = c1;
            }
        }
        __threadfence_block();
    }
}

// ---------------- flash attention (S^T, no-max softmax, MFMA l-sum) ----------------
template <bool TAIL>
__device__ __forceinline__ void attn_tile(
    const unsigned short* __restrict__ Ktile,  // LDS [64 key][64 dh], chunk-swizzled
    const unsigned short* __restrict__ Vtb,    // LDS V^T [80 rows][80 keys]; row64=ones
    unsigned short* __restrict__ Pqw,          // per-wave [16 q][72 keys]
    const short8& qf0, const short8& qf1,
    int quad, int lc,
    f32x4 (&oacc)[4], f32x4& lacc) {

    const int sw = lc & 7;
    f32x4 sfr[4];
    __builtin_amdgcn_s_setprio(1);
#pragma unroll
    for (int f = 0; f < 4; ++f) {
        const unsigned short* kr = Ktile + (f * 16 + lc) * 64;
        short8 k0 = *(const short8*)(kr + (quad ^ sw) * 8);
        short8 k1 = *(const short8*)(kr + ((quad ^ 4) ^ sw) * 8);
        f32x4 z = {};
        z = __builtin_amdgcn_mfma_f32_16x16x32_bf16(k0, qf0, z, 0, 0, 0);
        z = __builtin_amdgcn_mfma_f32_16x16x32_bf16(k1, qf1, z, 0, 0, 0);
        sfr[f] = z;
    }
    __builtin_amdgcn_s_setprio(0);

#pragma unroll
    for (int f = 0; f < 4; ++f) {
        float p[4];
#pragma unroll
        for (int r = 0; r < 4; ++r) {
            float s = sfr[f][r];
            if (TAIL && !(f == 0 && r == 0 && quad == 0)) s = -1e30f;
            p[r] = __builtin_amdgcn_exp2f(s * SCALE_L2E);
        }
        ushort2 lo = f2b2(p[0], p[1]), hi = f2b2(p[2], p[3]);
        ushort4 pk = {lo.x, lo.y, hi.x, hi.y};
        *(ushort4*)&Pqw[lc * 72 + f * 16 + quad * 4] = pk;
    }

    __threadfence_block();

    short8 pf0 = *(const short8*)&Pqw[lc * 72 + quad * 8];
    short8 pf1 = *(const short8*)&Pqw[lc * 72 + 32 + quad * 8];
    __builtin_amdgcn_s_setprio(1);
#pragma unroll
    for (int g = 0; g < 4; ++g) {
        short8 vf0 = *(const short8*)&Vtb[(g * 16 + lc) * 80 + quad * 8];
        short8 vf1 = *(const short8*)&Vtb[(g * 16 + lc) * 80 + 32 + quad * 8];
        oacc[g] = __builtin_amdgcn_mfma_f32_16x16x32_bf16(vf0, pf0, oacc[g], 0, 0, 0);
        oacc[g] = __builtin_amdgcn_mfma_f32_16x16x32_bf16(vf1, pf1, oacc[g], 0, 0, 0);
    }
    short8 vo0 = *(const short8*)&Vtb[(64 + lc) * 80 + quad * 8];
    short8 vo1 = *(const short8*)&Vtb[(64 + lc) * 80 + 32 + quad * 8];
    lacc = __builtin_amdgcn_mfma_f32_16x16x32_bf16(vo0, pf0, lacc, 0, 0, 0);
    lacc = __builtin_amdgcn_mfma_f32_16x16x32_bf16(vo1, pf1, lacc, 0, 0, 0);
    __builtin_amdgcn_s_setprio(0);
}

__global__ __launch_bounds__(512)
void attn_kernel(const unsigned short* __restrict__ qkv,   // [Mm][2304] bf16
                 unsigned short* __restrict__ outb) {      // [Mm][768] bf16
    __shared__ unsigned short Kt[2][64 * 64];
    __shared__ unsigned short Vt[2][80 * 80];
    __shared__ unsigned short Pq[8][16 * 72];

    const int tid = threadIdx.x;
    const int wave = tid >> 6, lane = tid & 63;
    const int quad = lane >> 4, lc = lane & 15;

    const int orig = (blockIdx.z * gridDim.y + blockIdx.y) * gridDim.x + blockIdx.x;
    const int wgid = (orig & 7) * 240 + (orig >> 3);
    const int qt = wgid % 5;
    const int h  = (wgid / 5) % Hh;
    const int b  = wgid / (5 * Hh);

    const unsigned short* qkvK = qkv + (size_t)b * Ss * QKV_N + h * 64 + 768;
    const unsigned short* qkvV = qkvK + 768;

    const int krow = lane >> 3;
    const int gch = (lane & 7) ^ krow;

    const int qbase = qt * 128 + wave * 16;
    int qrow = qbase + lc; if (qrow > Ss - 1) qrow = Ss - 1;
    const unsigned short* qp = qkv + (size_t)(b * Ss + qrow) * QKV_N + h * 64;
    short8 qf0 = *(const short8*)(qp + quad * 8);
    short8 qf1 = *(const short8*)(qp + 32 + quad * 8);

    unsigned short* Pqw = Pq[wave];

    auto stage_K = [&](int tile, int buf) {
        int key = tile * 64 + wave * 8 + krow; if (key > Ss - 1) key = Ss - 1;
        const unsigned short* gp = qkvK + (size_t)key * QKV_N + gch * 8;
        load_lds_16(gp, (void*)&Kt[buf][wave * 512]);
    };
    auto load_V = [&](int tile) -> short8 {
        int key = tile * 64 + lane; if (key > Ss - 1) key = Ss - 1;
        return *(const short8*)(qkvV + (size_t)key * QKV_N + wave * 8);
    };
    auto write_V = [&](short8 v, int buf) {
#pragma unroll
        for (int j = 0; j < 8; ++j)
            Vt[buf][(wave * 8 + j) * 80 + lane] = (unsigned short)v[j];
    };

    if (tid < 80) {
        Vt[0][64 * 80 + tid] = 0x3F80;   // bf16 1.0
        Vt[1][64 * 80 + tid] = 0x3F80;
    }

    f32x4 oacc[4] = {};
    f32x4 lacc = {};

    stage_K(0, 0);
    write_V(load_V(0), 0);
    __syncthreads();

    for (int kb = 0; kb < 9; ++kb) {
        const int buf = kb & 1;
        stage_K(kb + 1, buf ^ 1);
        short8 vreg = load_V(kb + 1);
        attn_tile<false>(Kt[buf], Vt[buf], Pqw, qf0, qf1, quad, lc, oacc, lacc);
        write_V(vreg, buf ^ 1);
        __syncthreads();
    }
    attn_tile<true>(Kt[1], Vt[1], Pqw, qf0, qf1, quad, lc, oacc, lacc);

    float lq = __shfl(lacc[0], lc, 64);
    float inv = 1.f / lq;
#pragma unroll
    for (int g = 0; g < 4; ++g) {
        ushort2 lo = f2b2(oacc[g][0] * inv, oacc[g][1] * inv);
        ushort2 hi = f2b2(oacc[g][2] * inv, oacc[g][3] * inv);
        ushort4 ob = {lo.x, lo.y, hi.x, hi.y};
        *(ushort4*)&Pqw[lc * 72 + g * 16 + quad * 4] = ob;
    }
    __threadfence_block();
#pragma unroll
    for (int p = 0; p < 2; ++p) {
        int lr = p * 8 + (lane >> 3), ch = lane & 7;
        int q = qbase + lr;
        if (q <= Ss - 1) {
            short8 vv = *(const short8*)&Pqw[lr * 72 + ch * 8];
            *(short8*)(outb + (size_t)(b * Ss + q) * Dd + h * 64 + ch * 8) = vv;
        }
    }
}

extern "C" void kernel_launch(void* const* d_in, const int* in_sizes, int n_in,
                              void* d_out, int out_size, void* d_ws, size_t ws_size,
                              hipStream_t stream) {
    const float* x     = (const float*)d_in[0];
    const float* w_qkv = (const float*)d_in[1];
    const float* b_qkv = (const float*)d_in[2];
    const float* w_fc  = (const float*)d_in[3];
    const float* b_fc  = (const float*)d_in[4];

    uint8_t* ws = (uint8_t*)d_ws;
    unsigned short* xb    = (unsigned short*)(ws + 0);           //  28,360,704 B
    unsigned short* wqkvT = (unsigned short*)(ws + 28360704);    //   3,538,944 B
    unsigned short* wfcT  = (unsigned short*)(ws + 31899648);    //   1,179,648 B
    unsigned short* qkv   = (unsigned short*)(ws + 33079296);    //  85,082,112 B
    unsigned short* attn  = (unsigned short*)(ws + 118161408);   //  28,360,704 B

    // dynamic LDS opt-in (one-time; host-side, capture-safe)
    static bool lds_init = false;
    if (!lds_init) {
        hipFuncSetAttribute((const void*)gemm2ph<QKV_N, 256, true>,
                            hipFuncAttributeMaxDynamicSharedMemorySize, 65536);
        hipFuncSetAttribute((const void*)gemm2ph<Dd, 128, false>,
                            hipFuncAttributeMaxDynamicSharedMemorySize, 49152);
        lds_init = true;
    }

    int n4 = (Mm * Dd) / 4;
    cast_f32_bf16<<<(n4 + 255) / 256, 256, 0, stream>>>(x, xb, n4);
    transpose_cast<<<dim3(QKV_N / 32, Dd / 32), dim3(32, 8), 0, stream>>>(w_qkv, wqkvT, Dd, QKV_N);
    transpose_cast<<<dim3(Dd / 32, Dd / 32), dim3(32, 8), 0, stream>>>(w_fc, wfcT, Dd, Dd);

    gemm2ph<QKV_N, 256, true><<<dim3(QKV_N / 256, (Mm + 255) / 256), 512, 65536, stream>>>(xb, wqkvT, b_qkv, qkv);

    attn_kernel<<<dim3(5, Hh, Bz), 512, 0, stream>>>(qkv, attn);

    gemm2ph<Dd, 128, false><<<dim3(Dd / 128, (Mm + 255) / 256), 512, 49152, stream>>>(attn, wfcT, b_fc, d_out);
}

// Round 4
// 308.087 us; speedup vs baseline: 2.6506x; 2.6506x over previous
//
#include <hip/hip_runtime.h>
#include <hip/hip_bf16.h>
#include <stdint.h>

typedef __attribute__((ext_vector_type(8))) short short8;   // 8 bf16 = 4 VGPRs
typedef __attribute__((ext_vector_type(4))) float f32x4;    // MFMA C/D frag

typedef __attribute__((address_space(3))) uint8_t lds_u8;
typedef __attribute__((address_space(1))) uint8_t glb_u8;

__device__ __forceinline__ void load_lds_16(const void* g, void* l) {
    __builtin_amdgcn_global_load_lds((glb_u8*)g, (lds_u8*)l, 16, 0, 0);
}

__device__ __forceinline__ unsigned short f2b(float f) {
    __hip_bfloat16 h = __float2bfloat16(f);
    return __builtin_bit_cast(unsigned short, h);
}
__device__ __forceinline__ ushort2 f2b2(float a, float b) {
    __hip_bfloat162 h = __float22bfloat162_rn(float2{a, b});
    ushort2 r;
    __builtin_memcpy(&r, &h, sizeof(r));
    return r;
}
__device__ __forceinline__ float b2f(unsigned short u) {
    unsigned int x = ((unsigned int)u) << 16;
    return __builtin_bit_cast(float, x);
}

constexpr int Bz = 32, Ss = 577, Dd = 768, Hh = 12;
constexpr int Mm = Bz * Ss;          // 18464
constexpr int QKV_N = 3 * Dd;        // 2304
constexpr float SCALE_L2E = 0.125f * 1.4426950408889634f;

// ---------------- cast x -> bf16 ----------------
__global__ void cast_f32_bf16(const float* __restrict__ src,
                              unsigned short* __restrict__ dst, int n4) {
    int i = blockIdx.x * blockDim.x + threadIdx.x;
    if (i >= n4) return;
    float4 v = ((const float4*)src)[i];
    ushort4 o;
    o.x = f2b(v.x); o.y = f2b(v.y); o.z = f2b(v.z); o.w = f2b(v.w);
    ((ushort4*)dst)[i] = o;
}

// ---------------- transpose + cast: src fp32 [R][C] -> dst bf16 [C][R] ----------------
__global__ void transpose_cast(const float* __restrict__ src,
                               unsigned short* __restrict__ dst, int R, int C) {
    __shared__ unsigned short tile[32][33];
    int c0 = blockIdx.x * 32, r0 = blockIdx.y * 32;
    int tx = threadIdx.x, ty = threadIdx.y;  // (32,8)
#pragma unroll
    for (int i = 0; i < 4; ++i)
        tile[ty + i * 8][tx] = f2b(src[(size_t)(r0 + ty + i * 8) * C + c0 + tx]);
    __syncthreads();
#pragma unroll
    for (int i = 0; i < 4; ++i) {
        int rr = ty + i * 8;
        dst[(size_t)(c0 + rr) * R + r0 + tx] = tile[tx][rr];
    }
}

// ================= 256x256 8-phase TN GEMM (T2+T3+T4+T5) =================
// Verified r2 structure: 87 us QKV, MfmaUtil 31%, bank conflicts 0, FETCH at
// XCD-L2 ideal. 8 waves (2M x 4N), BK=64, 12 K-tiles, 128 KiB dynamic LDS.
// NOTE (r3 lesson): per-wave acc = 128 AGPR -> total regs ~244 -> 2 waves/SIMD
// -> 1 block/CU is the HARD occupancy ceiling for this tile shape. Do NOT
// request more via __launch_bounds__ (forces accumulator spill, 7x slowdown).
template <int N_, bool OUT_BF16>
__global__ __launch_bounds__(512, 2)
void gemm256(const unsigned short* __restrict__ A,
             const unsigned short* __restrict__ Bt,
             const float* __restrict__ bias,
             void* __restrict__ Cout) {
    constexpr int K = 768;
    constexpr int KB = 12;               // K / 64
    constexpr int NX = N_ / 256;
    constexpr int NY = (Mm + 255) / 256; // 73
    constexpr int NWG = NX * NY;
    constexpr int QC = NWG >> 3, RC = NWG & 7;
    extern __shared__ __align__(16) uint8_t smem[];   // 131072 B

    const int tid = threadIdx.x;
    const int wave = tid >> 6, lane = tid & 63;
    const int quad = lane >> 4, lc = lane & 15;
    const int wm = wave >> 2, wn = wave & 3;

    // XCD-aware bijective remap (m204)
    const int orig = blockIdx.y * NX + blockIdx.x;
    const int xcd = orig & 7, lid = orig >> 3;
    const int wgid = (xcd < RC ? xcd * (QC + 1) : RC * (QC + 1) + (xcd - RC) * QC) + lid;
    const int tm = (wgid / NX) * 256;
    const int tn = (wgid % NX) * 256;

    // staging geometry: packed row prs = (s*8+wave)*8 + (lane>>3), chunk = lane&7
    const int colsw = ((lane & 7) ^ (lane >> 3)) * 8;   // pre-swizzled k-chunk
    const unsigned short* rpA[2][2];
    const unsigned short* rpB[2][2];
#pragma unroll
    for (int s = 0; s < 2; ++s) {
        const int prs = (s * 8 + wave) * 8 + (lane >> 3);
#pragma unroll
        for (int h = 0; h < 2; ++h) {
            int ar = tm + (prs >> 6) * 128 + h * 64 + (prs & 63);
            if (ar >= Mm) ar = Mm - 1;                       // M-tail clamp
            rpA[s][h] = A + (size_t)ar * K + colsw;
            int br = tn + (prs >> 5) * 64 + h * 32 + (prs & 31);
            rpB[s][h] = Bt + (size_t)br * K + colsw;
        }
    }

    auto ldsA = [&](int b, int mh) -> uint8_t* { return smem + b * 65536 + mh * 16384; };
    auto ldsB = [&](int b, int nh) -> uint8_t* { return smem + b * 65536 + 32768 + nh * 16384; };

    auto stageA = [&](int kb, int mh) {
        uint8_t* d = ldsA(kb & 1, mh) + wave * 1024;
        load_lds_16(rpA[0][mh] + kb * 64, d);
        load_lds_16(rpA[1][mh] + kb * 64, d + 8192);
    };
    auto stageB = [&](int kb, int nh) {
        uint8_t* d = ldsB(kb & 1, nh) + wave * 1024;
        load_lds_16(rpB[0][nh] + kb * 64, d);
        load_lds_16(rpB[1][nh] + kb * 64, d + 8192);
    };

    short8 af[2][4], bf[2][2];
    auto readA = [&](int b, int mh) {
        const unsigned short* p = (const unsigned short*)ldsA(b, mh);
#pragma unroll
        for (int i = 0; i < 4; ++i) {
            const int pr = wm * 64 + i * 16 + lc;
            const unsigned short* r = p + pr * 64;
            const int sw = pr & 7;
            af[0][i] = *(const short8*)(r + ((quad) ^ sw) * 8);
            af[1][i] = *(const short8*)(r + ((4 + quad) ^ sw) * 8);
        }
    };
    auto readB = [&](int b, int nh) {
        const unsigned short* p = (const unsigned short*)ldsB(b, nh);
#pragma unroll
        for (int j = 0; j < 2; ++j) {
            const int pr = wn * 32 + j * 16 + lc;
            const unsigned short* r = p + pr * 64;
            const int sw = pr & 7;
            bf[0][j] = *(const short8*)(r + ((quad) ^ sw) * 8);
            bf[1][j] = *(const short8*)(r + ((4 + quad) ^ sw) * 8);
        }
    };

    f32x4 acc[8][4] = {};
    auto quadmfma = [&](int mh, int nh) {
        __builtin_amdgcn_s_setprio(1);
#pragma unroll
        for (int ks = 0; ks < 2; ++ks)
#pragma unroll
            for (int i = 0; i < 4; ++i)
#pragma unroll
                for (int j = 0; j < 2; ++j)
                    acc[mh * 4 + i][nh * 2 + j] = __builtin_amdgcn_mfma_f32_16x16x32_bf16(
                        af[ks][i], bf[ks][j], acc[mh * 4 + i][nh * 2 + j], 0, 0, 0);
        __builtin_amdgcn_s_setprio(0);
    };

    // ---- prologue: tile0 (A0,B1,A1,B0) + tile1 (A0,B1); wait tile0; barrier
    stageA(0, 0); stageB(0, 1); stageA(0, 1); stageB(0, 0);
    stageA(1, 0); stageB(1, 1);
    asm volatile("s_waitcnt vmcnt(4)" ::: "memory");
    __builtin_amdgcn_s_barrier();

    for (int T = 0; T < KB; ++T) {
        const int rb = T & 1;
        // ---- p0: (mh0, nh0) ; stage A1(T+1)
        readA(rb, 0); readB(rb, 0);
        if (T + 1 < KB) stageA(T + 1, 1);
        __builtin_amdgcn_s_barrier();
        asm volatile("s_waitcnt lgkmcnt(0)" ::: "memory");
        quadmfma(0, 0);
        __builtin_amdgcn_s_barrier();
        // ---- p1: (0,1) ; stage B0(T+1)
        readB(rb, 1);
        if (T + 1 < KB) stageB(T + 1, 0);
        __builtin_amdgcn_s_barrier();
        asm volatile("s_waitcnt lgkmcnt(0)" ::: "memory");
        quadmfma(0, 1);
        __builtin_amdgcn_s_barrier();
        // ---- p2: (1,1) ; stage A0(T+2)
        readA(rb, 1);
        if (T + 2 < KB) stageA(T + 2, 0);
        __builtin_amdgcn_s_barrier();
        asm volatile("s_waitcnt lgkmcnt(0)" ::: "memory");
        quadmfma(1, 1);
        __builtin_amdgcn_s_barrier();
        // ---- p3: (1,0) ; stage B1(T+2) ; boundary vmcnt
        readB(rb, 0);
        if (T + 2 < KB) stageB(T + 2, 1);
        __builtin_amdgcn_s_barrier();
        asm volatile("s_waitcnt lgkmcnt(0)" ::: "memory");
        quadmfma(1, 0);
        if (T + 2 < KB) { asm volatile("s_waitcnt vmcnt(4)" ::: "memory"); }
        else            { asm volatile("s_waitcnt vmcnt(0)" ::: "memory"); }
        __builtin_amdgcn_s_barrier();
    }

    // ---- epilogue: wave-private LDS transpose (reuses buf0 region), vector stores
    float bv[4];
#pragma unroll
    for (int j = 0; j < 4; ++j) bv[j] = bias[tn + wn * 64 + j * 16 + lc];

    float* ep = (float*)smem + wave * (16 * 68);   // 4352 B/wave
    const int erow = lane >> 2, ec = (lane & 3) * 16;
#pragma unroll
    for (int ia = 0; ia < 8; ++ia) {
#pragma unroll
        for (int j = 0; j < 4; ++j)
#pragma unroll
            for (int r = 0; r < 4; ++r)
                ep[(quad * 4 + r) * 68 + j * 16 + lc] = acc[ia][j][r] + bv[j];
        __threadfence_block();   // wave-local LDS ordering
        int grow = tm + wm * 128 + ia * 16 + erow;
        if (grow < Mm) {
            float4 c0 = *(float4*)&ep[erow * 68 + ec + 0];
            float4 c1 = *(float4*)&ep[erow * 68 + ec + 4];
            float4 c2 = *(float4*)&ep[erow * 68 + ec + 8];
            float4 c3 = *(float4*)&ep[erow * 68 + ec + 12];
            int gcol = tn + wn * 64 + ec;
            if constexpr (OUT_BF16) {
                unsigned short o[16];
                *(ushort2*)&o[0]  = f2b2(c0.x, c0.y);
                *(ushort2*)&o[2]  = f2b2(c0.z, c0.w);
                *(ushort2*)&o[4]  = f2b2(c1.x, c1.y);
                *(ushort2*)&o[6]  = f2b2(c1.z, c1.w);
                *(ushort2*)&o[8]  = f2b2(c2.x, c2.y);
                *(ushort2*)&o[10] = f2b2(c2.z, c2.w);
                *(ushort2*)&o[12] = f2b2(c3.x, c3.y);
                *(ushort2*)&o[14] = f2b2(c3.z, c3.w);
                unsigned short* op = (unsigned short*)Cout + (size_t)grow * N_ + gcol;
                *(short8*)(op + 0) = *(short8*)&o[0];
                *(short8*)(op + 8) = *(short8*)&o[8];
            } else {
                float* op = (float*)Cout + (size_t)grow * N_ + gcol;
                *(float4*)(op + 0)  = c0;
                *(float4*)(op + 4)  = c1;
                *(float4*)(op + 8)  = c2;
                *(float4*)(op + 12) = c3;
            }
        }
        __threadfence_block();
    }
}

// ---------------- flash attention (S^T, no-max softmax, MFMA l-sum) ----------------
// 9 full tiles cover keys 0..575; key 576 is handled by a ~70-op VALU tail
// (saves the former 10th tile: full staging + 18 MFMAs + barrier for ONE key).
__device__ __forceinline__ void attn_tile(
    const unsigned short* __restrict__ Ktile,  // LDS [64 key][64 dh], chunk-swizzled
    const unsigned short* __restrict__ Vtb,    // LDS V^T [80 rows][80 keys]; row64=ones
    unsigned short* __restrict__ Pqw,          // per-wave [16 q][72 keys]
    const short8& qf0, const short8& qf1,
    int quad, int lc,
    f32x4 (&oacc)[4], f32x4& lacc) {

    const int sw = lc & 7;
    f32x4 sfr[4];
    __builtin_amdgcn_s_setprio(1);
#pragma unroll
    for (int f = 0; f < 4; ++f) {
        const unsigned short* kr = Ktile + (f * 16 + lc) * 64;
        short8 k0 = *(const short8*)(kr + (quad ^ sw) * 8);
        short8 k1 = *(const short8*)(kr + ((quad ^ 4) ^ sw) * 8);
        f32x4 z = {};
        z = __builtin_amdgcn_mfma_f32_16x16x32_bf16(k0, qf0, z, 0, 0, 0);
        z = __builtin_amdgcn_mfma_f32_16x16x32_bf16(k1, qf1, z, 0, 0, 0);
        sfr[f] = z;
    }
    __builtin_amdgcn_s_setprio(0);

#pragma unroll
    for (int f = 0; f < 4; ++f) {
        float p[4];
#pragma unroll
        for (int r = 0; r < 4; ++r)
            p[r] = __builtin_amdgcn_exp2f(sfr[f][r] * SCALE_L2E);
        ushort2 lo = f2b2(p[0], p[1]), hi = f2b2(p[2], p[3]);
        ushort4 pk = {lo.x, lo.y, hi.x, hi.y};
        *(ushort4*)&Pqw[lc * 72 + f * 16 + quad * 4] = pk;
    }

    __threadfence_block();

    short8 pf0 = *(const short8*)&Pqw[lc * 72 + quad * 8];
    short8 pf1 = *(const short8*)&Pqw[lc * 72 + 32 + quad * 8];
    __builtin_amdgcn_s_setprio(1);
#pragma unroll
    for (int g = 0; g < 4; ++g) {
        short8 vf0 = *(const short8*)&Vtb[(g * 16 + lc) * 80 + quad * 8];
        short8 vf1 = *(const short8*)&Vtb[(g * 16 + lc) * 80 + 32 + quad * 8];
        oacc[g] = __builtin_amdgcn_mfma_f32_16x16x32_bf16(vf0, pf0, oacc[g], 0, 0, 0);
        oacc[g] = __builtin_amdgcn_mfma_f32_16x16x32_bf16(vf1, pf1, oacc[g], 0, 0, 0);
    }
    short8 vo0 = *(const short8*)&Vtb[(64 + lc) * 80 + quad * 8];
    short8 vo1 = *(const short8*)&Vtb[(64 + lc) * 80 + 32 + quad * 8];
    lacc = __builtin_amdgcn_mfma_f32_16x16x32_bf16(vo0, pf0, lacc, 0, 0, 0);
    lacc = __builtin_amdgcn_mfma_f32_16x16x32_bf16(vo1, pf1, lacc, 0, 0, 0);
    __builtin_amdgcn_s_setprio(0);
}

__global__ __launch_bounds__(512)
void attn_kernel(const unsigned short* __restrict__ qkv,   // [Mm][2304] bf16
                 unsigned short* __restrict__ outb) {      // [Mm][768] bf16
    __shared__ unsigned short Kt[2][64 * 64];
    __shared__ unsigned short Vt[2][80 * 80];
    __shared__ unsigned short Pq[8][16 * 72];

    const int tid = threadIdx.x;
    const int wave = tid >> 6, lane = tid & 63;
    const int quad = lane >> 4, lc = lane & 15;

    const int orig = (blockIdx.z * gridDim.y + blockIdx.y) * gridDim.x + blockIdx.x;
    const int wgid = (orig & 7) * 240 + (orig >> 3);
    const int qt = wgid % 5;
    const int h  = (wgid / 5) % Hh;
    const int b  = wgid / (5 * Hh);

    const unsigned short* qkvK = qkv + (size_t)b * Ss * QKV_N + h * 64 + 768;
    const unsigned short* qkvV = qkvK + 768;

    const int krow = lane >> 3;
    const int gch = (lane & 7) ^ krow;

    const int qbase = qt * 128 + wave * 16;
    int qrow = qbase + lc; if (qrow > Ss - 1) qrow = Ss - 1;
    const unsigned short* qp = qkv + (size_t)(b * Ss + qrow) * QKV_N + h * 64;
    short8 qf0 = *(const short8*)(qp + quad * 8);
    short8 qf1 = *(const short8*)(qp + 32 + quad * 8);

    unsigned short* Pqw = Pq[wave];

    auto stage_K = [&](int tile, int buf) {
        int key = tile * 64 + wave * 8 + krow;       // tile<=8 -> key<=575, in range
        const unsigned short* gp = qkvK + (size_t)key * QKV_N + gch * 8;
        load_lds_16(gp, (void*)&Kt[buf][wave * 512]);
    };
    auto load_V = [&](int tile) -> short8 {
        int key = tile * 64 + lane;                  // tile<=8 -> key<=575
        return *(const short8*)(qkvV + (size_t)key * QKV_N + wave * 8);
    };
    auto write_V = [&](short8 v, int buf) {
#pragma unroll
        for (int j = 0; j < 8; ++j)
            Vt[buf][(wave * 8 + j) * 80 + lane] = (unsigned short)v[j];
    };

    if (tid < 80) {
        Vt[0][64 * 80 + tid] = 0x3F80;   // bf16 1.0
        Vt[1][64 * 80 + tid] = 0x3F80;
    }

    f32x4 oacc[4] = {};
    f32x4 lacc = {};

    stage_K(0, 0);
    write_V(load_V(0), 0);
    __syncthreads();

    for (int kb = 0; kb < 8; ++kb) {
        const int buf = kb & 1;
        stage_K(kb + 1, buf ^ 1);
        short8 vreg = load_V(kb + 1);
        attn_tile(Kt[buf], Vt[buf], Pqw, qf0, qf1, quad, lc, oacc, lacc);
        write_V(vreg, buf ^ 1);
        __syncthreads();
    }
    attn_tile(Kt[0], Vt[0], Pqw, qf0, qf1, quad, lc, oacc, lacc);   // tile 8 (buf 0)

    // ---- key 576 in registers: p = exp2(q.k576 * C); l += p; O^T[:,q] += p*v576
    float ptail;
    {
        const unsigned short* k576 = qkvK + (size_t)576 * QKV_N;
        short8 kk0 = *(const short8*)(k576 + quad * 8);
        short8 kk1 = *(const short8*)(k576 + 32 + quad * 8);
        float part = 0.f;
#pragma unroll
        for (int j = 0; j < 8; ++j)
            part += b2f((unsigned short)qf0[j]) * b2f((unsigned short)kk0[j])
                  + b2f((unsigned short)qf1[j]) * b2f((unsigned short)kk1[j]);
        part += __shfl_xor(part, 16, 64);
        part += __shfl_xor(part, 32, 64);           // full dot for q-row lc, all quads
        ptail = __builtin_amdgcn_exp2f(part * SCALE_L2E);
        const unsigned short* v576 = qkvV + (size_t)576 * QKV_N;
#pragma unroll
        for (int g = 0; g < 4; ++g) {
            ushort4 vv = *(const ushort4*)(v576 + g * 16 + quad * 4);
            oacc[g][0] += ptail * b2f(vv.x);
            oacc[g][1] += ptail * b2f(vv.y);
            oacc[g][2] += ptail * b2f(vv.z);
            oacc[g][3] += ptail * b2f(vv.w);
        }
    }

    // ---- epilogue: l broadcast (+tail), O^T -> LDS transpose -> coalesced store
    float lq = __shfl(lacc[0], lc, 64) + ptail;   // l[q] from lanes 0..15 + tail p
    float inv = 1.f / lq;
#pragma unroll
    for (int g = 0; g < 4; ++g) {
        ushort2 lo = f2b2(oacc[g][0] * inv, oacc[g][1] * inv);
        ushort2 hi = f2b2(oacc[g][2] * inv, oacc[g][3] * inv);
        ushort4 ob = {lo.x, lo.y, hi.x, hi.y};
        *(ushort4*)&Pqw[lc * 72 + g * 16 + quad * 4] = ob;
    }
    __threadfence_block();
#pragma unroll
    for (int p = 0; p < 2; ++p) {
        int lr = p * 8 + (lane >> 3), ch = lane & 7;
        int q = qbase + lr;
        if (q <= Ss - 1) {
            short8 vv = *(const short8*)&Pqw[lr * 72 + ch * 8];
            *(short8*)(outb + (size_t)(b * Ss + q) * Dd + h * 64 + ch * 8) = vv;
        }
    }
}

extern "C" void kernel_launch(void* const* d_in, const int* in_sizes, int n_in,
                              void* d_out, int out_size, void* d_ws, size_t ws_size,
                              hipStream_t stream) {
    const float* x     = (const float*)d_in[0];
    const float* w_qkv = (const float*)d_in[1];
    const float* b_qkv = (const float*)d_in[2];
    const float* w_fc  = (const float*)d_in[3];
    const float* b_fc  = (const float*)d_in[4];

    uint8_t* ws = (uint8_t*)d_ws;
    unsigned short* xb    = (unsigned short*)(ws + 0);           //  28,360,704 B
    unsigned short* wqkvT = (unsigned short*)(ws + 28360704);    //   3,538,944 B
    unsigned short* wfcT  = (unsigned short*)(ws + 31899648);    //   1,179,648 B
    unsigned short* qkv   = (unsigned short*)(ws + 33079296);    //  85,082,112 B
    unsigned short* attn  = (unsigned short*)(ws + 118161408);   //  28,360,704 B

    // 128 KiB dynamic LDS opt-in (one-time; host-side, capture-safe)
    static bool lds_init = false;
    if (!lds_init) {
        hipFuncSetAttribute((const void*)gemm256<QKV_N, true>,
                            hipFuncAttributeMaxDynamicSharedMemorySize, 131072);
        hipFuncSetAttribute((const void*)gemm256<Dd, false>,
                            hipFuncAttributeMaxDynamicSharedMemorySize, 131072);
        lds_init = true;
    }

    int n4 = (Mm * Dd) / 4;
    cast_f32_bf16<<<(n4 + 255) / 256, 256, 0, stream>>>(x, xb, n4);
    transpose_cast<<<dim3(QKV_N / 32, Dd / 32), dim3(32, 8), 0, stream>>>(w_qkv, wqkvT, Dd, QKV_N);
    transpose_cast<<<dim3(Dd / 32, Dd / 32), dim3(32, 8), 0, stream>>>(w_fc, wfcT, Dd, Dd);

    gemm256<QKV_N, true><<<dim3(QKV_N / 256, (Mm + 255) / 256), 512, 131072, stream>>>(xb, wqkvT, b_qkv, qkv);

    attn_kernel<<<dim3(5, Hh, Bz), 512, 0, stream>>>(qkv, attn);

    gemm256<Dd, false><<<dim3(Dd / 256, (Mm + 255) / 256), 512, 131072, stream>>>(attn, wfcT, b_fc, d_out);
}

// Round 5
// 307.989 us; speedup vs baseline: 2.6514x; 1.0003x over previous
//
#include <hip/hip_runtime.h>
#include <hip/hip_bf16.h>
#include <stdint.h>

typedef __attribute__((ext_vector_type(8))) short short8;   // 8 bf16 = 4 VGPRs
typedef __attribute__((ext_vector_type(4))) float f32x4;    // MFMA C/D frag

typedef __attribute__((address_space(3))) uint8_t lds_u8;
typedef __attribute__((address_space(1))) uint8_t glb_u8;

__device__ __forceinline__ void load_lds_16(const void* g, void* l) {
    __builtin_amdgcn_global_load_lds((glb_u8*)g, (lds_u8*)l, 16, 0, 0);
}

__device__ __forceinline__ unsigned short f2b(float f) {
    __hip_bfloat16 h = __float2bfloat16(f);
    return __builtin_bit_cast(unsigned short, h);
}
__device__ __forceinline__ ushort2 f2b2(float a, float b) {
    __hip_bfloat162 h = __float22bfloat162_rn(float2{a, b});
    ushort2 r;
    __builtin_memcpy(&r, &h, sizeof(r));
    return r;
}
__device__ __forceinline__ float b2f(unsigned short u) {
    unsigned int x = ((unsigned int)u) << 16;
    return __builtin_bit_cast(float, x);
}

constexpr int Bz = 32, Ss = 577, Dd = 768, Hh = 12;
constexpr int Mm = Bz * Ss;          // 18464
constexpr int QKV_N = 3 * Dd;        // 2304
constexpr float SCALE_L2E = 0.125f * 1.4426950408889634f;

// ---------------- cast x -> bf16 ----------------
__global__ void cast_f32_bf16(const float* __restrict__ src,
                              unsigned short* __restrict__ dst, int n4) {
    int i = blockIdx.x * blockDim.x + threadIdx.x;
    if (i >= n4) return;
    float4 v = ((const float4*)src)[i];
    ushort4 o;
    o.x = f2b(v.x); o.y = f2b(v.y); o.z = f2b(v.z); o.w = f2b(v.w);
    ((ushort4*)dst)[i] = o;
}

// ---------------- transpose + cast: src fp32 [R][C] -> dst bf16 [C][R] ----------------
__global__ void transpose_cast(const float* __restrict__ src,
                               unsigned short* __restrict__ dst, int R, int C) {
    __shared__ unsigned short tile[32][33];
    int c0 = blockIdx.x * 32, r0 = blockIdx.y * 32;
    int tx = threadIdx.x, ty = threadIdx.y;  // (32,8)
#pragma unroll
    for (int i = 0; i < 4; ++i)
        tile[ty + i * 8][tx] = f2b(src[(size_t)(r0 + ty + i * 8) * C + c0 + tx]);
    __syncthreads();
#pragma unroll
    for (int i = 0; i < 4; ++i) {
        int rr = ty + i * 8;
        dst[(size_t)(c0 + rr) * R + r0 + tx] = tile[tx][rr];
    }
}

// ============ 256x256 single-barrier-per-K-tile TN GEMM (T1+T2+T5) ============
// C[M][N_] = A[M][768] * Bt[N_][768]^T + bias.
// 8 waves (2M x 4N), BK=64, 12 K-tiles, 128 KiB dynamic LDS (2 bufs).
// r4's 8-phase variant measured 6.7k cyc/K-tile vs the ~2.7k LDS-read floor:
// the 8 barriers/K-tile + blanket lgkmcnt(0) drains exposed ~3k cyc/tile of
// LDS thundering-herd latency. This version: ONE barrier per K-tile; plain
// C++ ds_reads (compiler emits per-dependency lgkmcnt(N)); stages issued at
// tile start, drained by a single vmcnt(0) covered by the whole tile's
// MFMA+read span (~1.5k cyc >> HBM ~900). Race ledger: all reads of buf T
// complete before T's end barrier (MFMA operands); stages for T+1 drain at
// the same vmcnt(0); buffers only re-staged one tile after last read retires.
// NOTE (r3 lesson): per-wave acc = 128 regs (unified VGPR/AGPR) -> 2 waves/
// SIMD is the hard ceiling; keep __launch_bounds__(512,2), never demand more.
template <int N_, bool OUT_BF16>
__global__ __launch_bounds__(512, 2)
void gemm256(const unsigned short* __restrict__ A,
             const unsigned short* __restrict__ Bt,
             const float* __restrict__ bias,
             void* __restrict__ Cout) {
    constexpr int K = 768;
    constexpr int KB = 12;               // K / 64
    constexpr int NX = N_ / 256;
    constexpr int NY = (Mm + 255) / 256; // 73
    constexpr int NWG = NX * NY;
    constexpr int QC = NWG >> 3, RC = NWG & 7;
    extern __shared__ __align__(16) uint8_t smem[];   // 131072 B

    const int tid = threadIdx.x;
    const int wave = tid >> 6, lane = tid & 63;
    const int quad = lane >> 4, lc = lane & 15;
    const int wm = wave >> 2, wn = wave & 3;

    // XCD-aware bijective remap (m204)
    const int orig = blockIdx.y * NX + blockIdx.x;
    const int xcd = orig & 7, lid = orig >> 3;
    const int wgid = (xcd < RC ? xcd * (QC + 1) : RC * (QC + 1) + (xcd - RC) * QC) + lid;
    const int tm = (wgid / NX) * 256;
    const int tn = (wgid % NX) * 256;

    // staging geometry: packed row prs = (s*8+wave)*8 + (lane>>3), chunk = lane&7
    const int colsw = ((lane & 7) ^ (lane >> 3)) * 8;   // pre-swizzled k-chunk
    const unsigned short* rpA[2][2];
    const unsigned short* rpB[2][2];
#pragma unroll
    for (int s = 0; s < 2; ++s) {
        const int prs = (s * 8 + wave) * 8 + (lane >> 3);
#pragma unroll
        for (int h = 0; h < 2; ++h) {
            int ar = tm + (prs >> 6) * 128 + h * 64 + (prs & 63);
            if (ar >= Mm) ar = Mm - 1;                       // M-tail clamp
            rpA[s][h] = A + (size_t)ar * K + colsw;
            int br = tn + (prs >> 5) * 64 + h * 32 + (prs & 31);
            rpB[s][h] = Bt + (size_t)br * K + colsw;
        }
    }

    auto ldsA = [&](int b, int mh) -> uint8_t* { return smem + b * 65536 + mh * 16384; };
    auto ldsB = [&](int b, int nh) -> uint8_t* { return smem + b * 65536 + 32768 + nh * 16384; };

    auto stageA = [&](int kb, int mh) {
        uint8_t* d = ldsA(kb & 1, mh) + wave * 1024;
        load_lds_16(rpA[0][mh] + kb * 64, d);
        load_lds_16(rpA[1][mh] + kb * 64, d + 8192);
    };
    auto stageB = [&](int kb, int nh) {
        uint8_t* d = ldsB(kb & 1, nh) + wave * 1024;
        load_lds_16(rpB[0][nh] + kb * 64, d);
        load_lds_16(rpB[1][nh] + kb * 64, d + 8192);
    };

    short8 af[2][4], bf[2][2];
    auto readA = [&](int b, int mh) {
        const unsigned short* p = (const unsigned short*)ldsA(b, mh);
#pragma unroll
        for (int i = 0; i < 4; ++i) {
            const int pr = wm * 64 + i * 16 + lc;
            const unsigned short* r = p + pr * 64;
            const int sw = pr & 7;
            af[0][i] = *(const short8*)(r + ((quad) ^ sw) * 8);
            af[1][i] = *(const short8*)(r + ((4 + quad) ^ sw) * 8);
        }
    };
    auto readB = [&](int b, int nh) {
        const unsigned short* p = (const unsigned short*)ldsB(b, nh);
#pragma unroll
        for (int j = 0; j < 2; ++j) {
            const int pr = wn * 32 + j * 16 + lc;
            const unsigned short* r = p + pr * 64;
            const int sw = pr & 7;
            bf[0][j] = *(const short8*)(r + ((quad) ^ sw) * 8);
            bf[1][j] = *(const short8*)(r + ((4 + quad) ^ sw) * 8);
        }
    };

    f32x4 acc[8][4] = {};
    auto quadmfma = [&](int mh, int nh) {
        __builtin_amdgcn_s_setprio(1);
#pragma unroll
        for (int ks = 0; ks < 2; ++ks)
#pragma unroll
            for (int i = 0; i < 4; ++i)
#pragma unroll
                for (int j = 0; j < 2; ++j)
                    acc[mh * 4 + i][nh * 2 + j] = __builtin_amdgcn_mfma_f32_16x16x32_bf16(
                        af[ks][i], bf[ks][j], acc[mh * 4 + i][nh * 2 + j], 0, 0, 0);
        __builtin_amdgcn_s_setprio(0);
    };

    // ---- prologue: stage tile0 fully, publish
    stageA(0, 0); stageA(0, 1); stageB(0, 0); stageB(0, 1);
    asm volatile("s_waitcnt vmcnt(0)" ::: "memory");
    __builtin_amdgcn_s_barrier();
    __builtin_amdgcn_sched_barrier(0);

    for (int T = 0; T < KB; ++T) {
        const int rb = T & 1;
        // reads of current buf; stages for T+1 into the other buf.
        readA(rb, 0);
        readB(rb, 0);
        if (T + 1 < KB) {
            stageA(T + 1, 0); stageA(T + 1, 1);
            stageB(T + 1, 0); stageB(T + 1, 1);
        }
        quadmfma(0, 0);
        readB(rb, 1);
        quadmfma(0, 1);
        readA(rb, 1);
        quadmfma(1, 1);
        readB(rb, 0);
        quadmfma(1, 0);
        // single drain + publish: covered by the tile's full MFMA/read span
        asm volatile("s_waitcnt vmcnt(0)" ::: "memory");
        __builtin_amdgcn_s_barrier();
        __builtin_amdgcn_sched_barrier(0);
    }

    // ---- epilogue: wave-private LDS transpose (reuses buf0 region), vector stores
    float bv[4];
#pragma unroll
    for (int j = 0; j < 4; ++j) bv[j] = bias[tn + wn * 64 + j * 16 + lc];

    float* ep = (float*)smem + wave * (16 * 68);   // 4352 B/wave
    const int erow = lane >> 2, ec = (lane & 3) * 16;
#pragma unroll
    for (int ia = 0; ia < 8; ++ia) {
#pragma unroll
        for (int j = 0; j < 4; ++j)
#pragma unroll
            for (int r = 0; r < 4; ++r)
                ep[(quad * 4 + r) * 68 + j * 16 + lc] = acc[ia][j][r] + bv[j];
        __threadfence_block();   // wave-local LDS ordering
        int grow = tm + wm * 128 + ia * 16 + erow;
        if (grow < Mm) {
            float4 c0 = *(float4*)&ep[erow * 68 + ec + 0];
            float4 c1 = *(float4*)&ep[erow * 68 + ec + 4];
            float4 c2 = *(float4*)&ep[erow * 68 + ec + 8];
            float4 c3 = *(float4*)&ep[erow * 68 + ec + 12];
            int gcol = tn + wn * 64 + ec;
            if constexpr (OUT_BF16) {
                unsigned short o[16];
                *(ushort2*)&o[0]  = f2b2(c0.x, c0.y);
                *(ushort2*)&o[2]  = f2b2(c0.z, c0.w);
                *(ushort2*)&o[4]  = f2b2(c1.x, c1.y);
                *(ushort2*)&o[6]  = f2b2(c1.z, c1.w);
                *(ushort2*)&o[8]  = f2b2(c2.x, c2.y);
                *(ushort2*)&o[10] = f2b2(c2.z, c2.w);
                *(ushort2*)&o[12] = f2b2(c3.x, c3.y);
                *(ushort2*)&o[14] = f2b2(c3.z, c3.w);
                unsigned short* op = (unsigned short*)Cout + (size_t)grow * N_ + gcol;
                *(short8*)(op + 0) = *(short8*)&o[0];
                *(short8*)(op + 8) = *(short8*)&o[8];
            } else {
                float* op = (float*)Cout + (size_t)grow * N_ + gcol;
                *(float4*)(op + 0)  = c0;
                *(float4*)(op + 4)  = c1;
                *(float4*)(op + 8)  = c2;
                *(float4*)(op + 12) = c3;
            }
        }
        __threadfence_block();
    }
}

// ---------------- flash attention (S^T, no-max softmax, MFMA l-sum) ----------------
// 9 full tiles cover keys 0..575; key 576 handled by a register VALU tail.
__device__ __forceinline__ void attn_tile(
    const unsigned short* __restrict__ Ktile,  // LDS [64 key][64 dh], chunk-swizzled
    const unsigned short* __restrict__ Vtb,    // LDS V^T [80 rows][80 keys]; row64=ones
    unsigned short* __restrict__ Pqw,          // per-wave [16 q][72 keys]
    const short8& qf0, const short8& qf1,
    int quad, int lc,
    f32x4 (&oacc)[4], f32x4& lacc) {

    const int sw = lc & 7;
    f32x4 sfr[4];
    __builtin_amdgcn_s_setprio(1);
#pragma unroll
    for (int f = 0; f < 4; ++f) {
        const unsigned short* kr = Ktile + (f * 16 + lc) * 64;
        short8 k0 = *(const short8*)(kr + (quad ^ sw) * 8);
        short8 k1 = *(const short8*)(kr + ((quad ^ 4) ^ sw) * 8);
        f32x4 z = {};
        z = __builtin_amdgcn_mfma_f32_16x16x32_bf16(k0, qf0, z, 0, 0, 0);
        z = __builtin_amdgcn_mfma_f32_16x16x32_bf16(k1, qf1, z, 0, 0, 0);
        sfr[f] = z;
    }
    __builtin_amdgcn_s_setprio(0);

#pragma unroll
    for (int f = 0; f < 4; ++f) {
        float p[4];
#pragma unroll
        for (int r = 0; r < 4; ++r)
            p[r] = __builtin_amdgcn_exp2f(sfr[f][r] * SCALE_L2E);
        ushort2 lo = f2b2(p[0], p[1]), hi = f2b2(p[2], p[3]);
        ushort4 pk = {lo.x, lo.y, hi.x, hi.y};
        *(ushort4*)&Pqw[lc * 72 + f * 16 + quad * 4] = pk;
    }

    __threadfence_block();

    short8 pf0 = *(const short8*)&Pqw[lc * 72 + quad * 8];
    short8 pf1 = *(const short8*)&Pqw[lc * 72 + 32 + quad * 8];
    __builtin_amdgcn_s_setprio(1);
#pragma unroll
    for (int g = 0; g < 4; ++g) {
        short8 vf0 = *(const short8*)&Vtb[(g * 16 + lc) * 80 + quad * 8];
        short8 vf1 = *(const short8*)&Vtb[(g * 16 + lc) * 80 + 32 + quad * 8];
        oacc[g] = __builtin_amdgcn_mfma_f32_16x16x32_bf16(vf0, pf0, oacc[g], 0, 0, 0);
        oacc[g] = __builtin_amdgcn_mfma_f32_16x16x32_bf16(vf1, pf1, oacc[g], 0, 0, 0);
    }
    short8 vo0 = *(const short8*)&Vtb[(64 + lc) * 80 + quad * 8];
    short8 vo1 = *(const short8*)&Vtb[(64 + lc) * 80 + 32 + quad * 8];
    lacc = __builtin_amdgcn_mfma_f32_16x16x32_bf16(vo0, pf0, lacc, 0, 0, 0);
    lacc = __builtin_amdgcn_mfma_f32_16x16x32_bf16(vo1, pf1, lacc, 0, 0, 0);
    __builtin_amdgcn_s_setprio(0);
}

__global__ __launch_bounds__(512)
void attn_kernel(const unsigned short* __restrict__ qkv,   // [Mm][2304] bf16
                 unsigned short* __restrict__ outb) {      // [Mm][768] bf16
    __shared__ unsigned short Kt[2][64 * 64];
    __shared__ unsigned short Vt[2][80 * 80];
    __shared__ unsigned short Pq[8][16 * 72];

    const int tid = threadIdx.x;
    const int wave = tid >> 6, lane = tid & 63;
    const int quad = lane >> 4, lc = lane & 15;

    const int orig = (blockIdx.z * gridDim.y + blockIdx.y) * gridDim.x + blockIdx.x;
    const int wgid = (orig & 7) * 240 + (orig >> 3);
    const int qt = wgid % 5;
    const int h  = (wgid / 5) % Hh;
    const int b  = wgid / (5 * Hh);

    const unsigned short* qkvK = qkv + (size_t)b * Ss * QKV_N + h * 64 + 768;
    const unsigned short* qkvV = qkvK + 768;

    const int krow = lane >> 3;
    const int gch = (lane & 7) ^ krow;

    const int qbase = qt * 128 + wave * 16;
    int qrow = qbase + lc; if (qrow > Ss - 1) qrow = Ss - 1;
    const unsigned short* qp = qkv + (size_t)(b * Ss + qrow) * QKV_N + h * 64;
    short8 qf0 = *(const short8*)(qp + quad * 8);
    short8 qf1 = *(const short8*)(qp + 32 + quad * 8);

    unsigned short* Pqw = Pq[wave];

    auto stage_K = [&](int tile, int buf) {
        int key = tile * 64 + wave * 8 + krow;       // tile<=8 -> key<=575, in range
        const unsigned short* gp = qkvK + (size_t)key * QKV_N + gch * 8;
        load_lds_16(gp, (void*)&Kt[buf][wave * 512]);
    };
    auto load_V = [&](int tile) -> short8 {
        int key = tile * 64 + lane;                  // tile<=8 -> key<=575
        return *(const short8*)(qkvV + (size_t)key * QKV_N + wave * 8);
    };
    auto write_V = [&](short8 v, int buf) {
#pragma unroll
        for (int j = 0; j < 8; ++j)
            Vt[buf][(wave * 8 + j) * 80 + lane] = (unsigned short)v[j];
    };

    if (tid < 80) {
        Vt[0][64 * 80 + tid] = 0x3F80;   // bf16 1.0
        Vt[1][64 * 80 + tid] = 0x3F80;
    }

    f32x4 oacc[4] = {};
    f32x4 lacc = {};

    stage_K(0, 0);
    write_V(load_V(0), 0);
    __syncthreads();

    for (int kb = 0; kb < 8; ++kb) {
        const int buf = kb & 1;
        stage_K(kb + 1, buf ^ 1);
        short8 vreg = load_V(kb + 1);
        attn_tile(Kt[buf], Vt[buf], Pqw, qf0, qf1, quad, lc, oacc, lacc);
        write_V(vreg, buf ^ 1);
        __syncthreads();
    }
    attn_tile(Kt[0], Vt[0], Pqw, qf0, qf1, quad, lc, oacc, lacc);   // tile 8 (buf 0)

    // ---- key 576 in registers: p = exp2(q.k576 * C); l += p; O^T[:,q] += p*v576
    float ptail;
    {
        const unsigned short* k576 = qkvK + (size_t)576 * QKV_N;
        short8 kk0 = *(const short8*)(k576 + quad * 8);
        short8 kk1 = *(const short8*)(k576 + 32 + quad * 8);
        float part = 0.f;
#pragma unroll
        for (int j = 0; j < 8; ++j)
            part += b2f((unsigned short)qf0[j]) * b2f((unsigned short)kk0[j])
                  + b2f((unsigned short)qf1[j]) * b2f((unsigned short)kk1[j]);
        part += __shfl_xor(part, 16, 64);
        part += __shfl_xor(part, 32, 64);           // full dot for q-row lc, all quads
        ptail = __builtin_amdgcn_exp2f(part * SCALE_L2E);
        const unsigned short* v576 = qkvV + (size_t)576 * QKV_N;
#pragma unroll
        for (int g = 0; g < 4; ++g) {
            ushort4 vv = *(const ushort4*)(v576 + g * 16 + quad * 4);
            oacc[g][0] += ptail * b2f(vv.x);
            oacc[g][1] += ptail * b2f(vv.y);
            oacc[g][2] += ptail * b2f(vv.z);
            oacc[g][3] += ptail * b2f(vv.w);
        }
    }

    // ---- epilogue: l broadcast (+tail), O^T -> LDS transpose -> coalesced store
    float lq = __shfl(lacc[0], lc, 64) + ptail;   // l[q] from lanes 0..15 + tail p
    float inv = 1.f / lq;
#pragma unroll
    for (int g = 0; g < 4; ++g) {
        ushort2 lo = f2b2(oacc[g][0] * inv, oacc[g][1] * inv);
        ushort2 hi = f2b2(oacc[g][2] * inv, oacc[g][3] * inv);
        ushort4 ob = {lo.x, lo.y, hi.x, hi.y};
        *(ushort4*)&Pqw[lc * 72 + g * 16 + quad * 4] = ob;
    }
    __threadfence_block();
#pragma unroll
    for (int p = 0; p < 2; ++p) {
        int lr = p * 8 + (lane >> 3), ch = lane & 7;
        int q = qbase + lr;
        if (q <= Ss - 1) {
            short8 vv = *(const short8*)&Pqw[lr * 72 + ch * 8];
            *(short8*)(outb + (size_t)(b * Ss + q) * Dd + h * 64 + ch * 8) = vv;
        }
    }
}

extern "C" void kernel_launch(void* const* d_in, const int* in_sizes, int n_in,
                              void* d_out, int out_size, void* d_ws, size_t ws_size,
                              hipStream_t stream) {
    const float* x     = (const float*)d_in[0];
    const float* w_qkv = (const float*)d_in[1];
    const float* b_qkv = (const float*)d_in[2];
    const float* w_fc  = (const float*)d_in[3];
    const float* b_fc  = (const float*)d_in[4];

    uint8_t* ws = (uint8_t*)d_ws;
    unsigned short* xb    = (unsigned short*)(ws + 0);           //  28,360,704 B
    unsigned short* wqkvT = (unsigned short*)(ws + 28360704);    //   3,538,944 B
    unsigned short* wfcT  = (unsigned short*)(ws + 31899648);    //   1,179,648 B
    unsigned short* qkv   = (unsigned short*)(ws + 33079296);    //  85,082,112 B
    unsigned short* attn  = (unsigned short*)(ws + 118161408);   //  28,360,704 B

    // 128 KiB dynamic LDS opt-in (one-time; host-side, capture-safe)
    static bool lds_init = false;
    if (!lds_init) {
        hipFuncSetAttribute((const void*)gemm256<QKV_N, true>,
                            hipFuncAttributeMaxDynamicSharedMemorySize, 131072);
        hipFuncSetAttribute((const void*)gemm256<Dd, false>,
                            hipFuncAttributeMaxDynamicSharedMemorySize, 131072);
        lds_init = true;
    }

    int n4 = (Mm * Dd) / 4;
    cast_f32_bf16<<<(n4 + 255) / 256, 256, 0, stream>>>(x, xb, n4);
    transpose_cast<<<dim3(QKV_N / 32, Dd / 32), dim3(32, 8), 0, stream>>>(w_qkv, wqkvT, Dd, QKV_N);
    transpose_cast<<<dim3(Dd / 32, Dd / 32), dim3(32, 8), 0, stream>>>(w_fc, wfcT, Dd, Dd);

    gemm256<QKV_N, true><<<dim3(QKV_N / 256, (Mm + 255) / 256), 512, 131072, stream>>>(xb, wqkvT, b_qkv, qkv);

    attn_kernel<<<dim3(5, Hh, Bz), 512, 0, stream>>>(qkv, attn);

    gemm256<Dd, false><<<dim3(Dd / 256, (Mm + 255) / 256), 512, 131072, stream>>>(attn, wfcT, b_fc, d_out);
}